// Round 11
// baseline (665.789 us; speedup 1.0000x reference)
//
#include <hip/hip_runtime.h>
#include <math.h>

#define NB 8
#define NN 2048

typedef short bf16x8 __attribute__((ext_vector_type(8)));
typedef float f32x4  __attribute__((ext_vector_type(4)));
typedef unsigned long long u64;

__device__ __forceinline__ f32x4 mfma16(uint4 a, uint4 b, f32x4 c) {
    return __builtin_amdgcn_mfma_f32_16x16x32_bf16(
        __builtin_bit_cast(bf16x8, a), __builtin_bit_cast(bf16x8, b), c, 0, 0, 0);
}

__device__ __forceinline__ float bf2f(unsigned short u) {
    unsigned int t = ((unsigned int)u) << 16;
    return __builtin_bit_cast(float, t);
}

__device__ __forceinline__ unsigned short f2bf_rne(float f) {
    unsigned int u = __builtin_bit_cast(unsigned int, f);
    return (unsigned short)((u + 0x7FFFu + ((u >> 16) & 1u)) >> 16);
}

__device__ __forceinline__ unsigned int rne_pair(unsigned int a, unsigned int b, unsigned int c) {
    float lo = bf2f((unsigned short)(a & 0xFFFF)) + bf2f((unsigned short)(b & 0xFFFF)) + bf2f((unsigned short)(c & 0xFFFF));
    float hi = bf2f((unsigned short)(a >> 16)) + bf2f((unsigned short)(b >> 16)) + bf2f((unsigned short)(c >> 16));
    return (unsigned int)f2bf_rne(lo) | ((unsigned int)f2bf_rne(hi) << 16);
}
__device__ __forceinline__ uint4 rne_merge(uint4 a, uint4 b, uint4 c) {
    return make_uint4(rne_pair(a.x, b.x, c.x), rne_pair(a.y, b.y, c.y),
                      rne_pair(a.z, b.z, c.z), rne_pair(a.w, b.w, c.w));
}

// monotone float->u32 key (ascending), then <<32 | j: u64 compare == (d, j) lexicographic
__device__ __forceinline__ u64 packdj(float d, int j) {
    unsigned int u = __builtin_bit_cast(unsigned int, d);
    unsigned int key = u ^ ((unsigned int)(((int)u) >> 31) | 0x80000000u);
    return ((u64)key << 32) | (unsigned int)j;
}

// Full sorted insert with jax tie-break (equal d -> smaller j) — for merges.
#define INS4(vv, ii, d, j) {                                      \
    bool c0 = (d < vv.x) || (d == vv.x && j < ii.x);              \
    bool c1 = (d < vv.y) || (d == vv.y && j < ii.y);              \
    bool c2 = (d < vv.z) || (d == vv.z && j < ii.z);              \
    bool c3 = (d < vv.w) || (d == vv.w && j < ii.w);              \
    vv.w = c3 ? (c2 ? vv.z : d) : vv.w; ii.w = c3 ? (c2 ? ii.z : j) : ii.w; \
    vv.z = c2 ? (c1 ? vv.y : d) : vv.z; ii.z = c2 ? (c1 ? ii.y : j) : ii.z; \
    vv.y = c1 ? (c0 ? vv.x : d) : vv.y; ii.y = c1 ? (c0 ? ii.x : j) : ii.y; \
    vv.x = c0 ? d : vv.x;               ii.x = c0 ? j : ii.x; }

// Strict-< insert: valid when candidates arrive in ascending j within a lane.
#define INS4S(vv, ii, d, j) {                                     \
    bool c0 = (d < vv.x); bool c1 = (d < vv.y);                   \
    bool c2 = (d < vv.z); bool c3 = (d < vv.w);                   \
    vv.w = c3 ? (c2 ? vv.z : d) : vv.w; ii.w = c3 ? (c2 ? ii.z : j) : ii.w; \
    vv.z = c2 ? (c1 ? vv.y : d) : vv.z; ii.z = c2 ? (c1 ? ii.y : j) : ii.z; \
    vv.y = c1 ? (c0 ? vv.x : d) : vv.y; ii.y = c1 ? (c0 ? ii.x : j) : ii.y; \
    vv.x = c0 ? d : vv.x;               ii.x = c0 ? j : ii.x; }

// sorted-4 u64 insert (strict <; entries are unique)
#define INSQ(a0, a1, a2, a3, p) {                                 \
    bool c0 = (p) < a0; bool c1 = (p) < a1;                       \
    bool c2 = (p) < a2; bool c3 = (p) < a3;                       \
    a3 = c3 ? (c2 ? a2 : (p)) : a3;                               \
    a2 = c2 ? (c1 ? a1 : (p)) : a2;                               \
    a1 = c1 ? (c0 ? a0 : (p)) : a1;                               \
    a0 = c0 ? (p) : a0; }

// ---------------- Kernel 0: weights -> bf16 MFMA B-frag images in workspace ----------------
// wfrag: [0,512) Wm frags; [512,2560) Wu1; [2560,4608) Wu2.
__global__ __launch_bounds__(256) void k_wprep(
    const float* __restrict__ Wm, const float* __restrict__ Wu1, const float* __restrict__ Wu2,
    uint4* __restrict__ wfrag)
{
    int q = blockIdx.x * 256 + threadIdx.x;   // 0..4607
    int ln = q & 63;
    int fr = ln & 15, qd = ln >> 4;
    unsigned int p[4];
    if (q < 512) {
        int fi2 = q >> 6;
        int fg = fi2 >> 1, hf = fi2 & 1;
        #pragma unroll
        for (int e2 = 0; e2 < 4; e2++) {
            unsigned int lo = f2bf_rne(Wm[(hf * 32 + qd * 8 + e2 * 2 + 0) * 64 + fg * 16 + fr]);
            unsigned int hi = f2bf_rne(Wm[(hf * 32 + qd * 8 + e2 * 2 + 1) * 64 + fg * 16 + fr]);
            p[e2] = lo | (hi << 16);
        }
    } else {
        int qq = q - 512;
        const float* W = (qq < 2048) ? Wu1 : Wu2;
        int q2 = qq & 2047;
        int fi2 = q2 >> 6;
        int fg = fi2 >> 2, kq = fi2 & 3;
        #pragma unroll
        for (int e2 = 0; e2 < 4; e2++) {
            unsigned int lo = f2bf_rne(W[(kq * 32 + qd * 8 + e2 * 2 + 0) * 128 + fg * 16 + fr]);
            unsigned int hi = f2bf_rne(W[(kq * 32 + qd * 8 + e2 * 2 + 1) * 128 + fg * 16 + fr]);
            p[e2] = lo | (hi << 16);
        }
    }
    wfrag[q] = make_uint4(p[0], p[1], p[2], p[3]);
}

// ---------------- Kernel 1: embed MLP; emit frag-major 3-split HsF + sq ----------------
__global__ __launch_bounds__(256) void k_embed(
    const float* __restrict__ x, const float* __restrict__ W1, const float* __restrict__ b1,
    const float* __restrict__ W2, const float* __restrict__ b2,
    uint4* __restrict__ HsF, float* __restrict__ sqv)
{
    __shared__ float w2s[4096];
    __shared__ float h1s[4][4][64];
    __shared__ unsigned short sh[3 * 16 * 72];
    int tid = threadIdx.x;
    for (int q = tid; q < 4096; q += 256) w2s[q] = W2[q];
    int wave = tid >> 6, lane = tid & 63;
    int nbase = blockIdx.x * 16 + wave * 4;
    float w10 = W1[lane], w11 = W1[64 + lane], w12 = W1[128 + lane], w13 = W1[192 + lane];
    float b1l = b1[lane];
    #pragma unroll
    for (int v = 0; v < 4; v++) {
        float4 xv = reinterpret_cast<const float4*>(x)[nbase + v];
        h1s[wave][v][lane] = fmaxf(b1l + xv.x * w10 + xv.y * w11 + xv.z * w12 + xv.w * w13, 0.f);
    }
    __syncthreads();
    float b2l = b2[lane];
    float a0 = b2l, a1 = b2l, a2 = b2l, a3 = b2l;
    for (int k = 0; k < 64; k++) {
        float w = w2s[k * 64 + lane];
        a0 += h1s[wave][0][k] * w; a1 += h1s[wave][1][k] * w;
        a2 += h1s[wave][2][k] * w; a3 += h1s[wave][3][k] * w;
    }
    float hvs[4] = {fmaxf(a0, 0.f), fmaxf(a1, 0.f), fmaxf(a2, 0.f), fmaxf(a3, 0.f)};
    #pragma unroll
    for (int v = 0; v < 4; v++) {
        float hval = hvs[v];
        long node = nbase + v;
        int row = wave * 4 + v;
        unsigned int u0 = __builtin_bit_cast(unsigned int, hval);
        unsigned short s0 = (unsigned short)(u0 >> 16);
        float f0 = __builtin_bit_cast(float, u0 & 0xFFFF0000u);
        float r1 = hval - f0;
        unsigned int u1 = __builtin_bit_cast(unsigned int, r1);
        unsigned short s1 = (unsigned short)(u1 >> 16);
        float f1 = __builtin_bit_cast(float, u1 & 0xFFFF0000u);
        float r2 = r1 - f1;
        unsigned short s2 = (unsigned short)(__builtin_bit_cast(unsigned int, r2) >> 16);
        sh[(0 * 16 + row) * 72 + lane] = s0;
        sh[(1 * 16 + row) * 72 + lane] = s1;
        sh[(2 * 16 + row) * 72 + lane] = s2;
        float s = hval * hval;
        #pragma unroll
        for (int m = 1; m < 64; m <<= 1) s += __shfl_xor(s, m, 64);
        if (lane == 0) sqv[node] = s;
    }
    __syncthreads();
    for (int q = tid; q < 384; q += 256) {
        int f = q >> 6, ln = q & 63;
        int s = f >> 1, hf = f & 1;
        int row = ln & 15, eb = hf * 32 + (ln >> 4) * 8;
        const unsigned short* sp = &sh[(s * 16 + row) * 72 + eb];
        unsigned int p0 = (unsigned int)sp[0] | ((unsigned int)sp[1] << 16);
        unsigned int p1 = (unsigned int)sp[2] | ((unsigned int)sp[3] << 16);
        unsigned int p2 = (unsigned int)sp[4] | ((unsigned int)sp[5] << 16);
        unsigned int p3 = (unsigned int)sp[6] | ((unsigned int)sp[7] << 16);
        HsF[((long)blockIdx.x * 6 + f) * 64 + ln] = make_uint4(p0, p1, p2, p3);
    }
}

// ---------------- Kernel 2: 3-NN partials via MFMA. No LDS, no barriers. ----------------
// wave job: 16 i-rows (1 group) x 512 j (1 of 4 splits). Fully-unrolled j-loop so the
// compiler pipelines B-frag loads deep ahead. Merge = register butterfly over l15.
// Output: packed u64 (flipfloat(d)<<32 | j) top-4 per (node, split).
__global__ __launch_bounds__(256, 3) void k_knn(
    const uint4* __restrict__ HsF, const float* __restrict__ sqv,
    u64* __restrict__ pk)
{
    int tid = threadIdx.x;
    int wave = tid >> 6, lane = tid & 63;
    int l15 = lane & 15, quad = lane >> 4;

    int bx = blockIdx.x;                 // 0..1023
    int js = bx & 3;
    int gquad = (bx >> 2) & 31;
    int b = bx >> 7;
    int gwb = gquad * 4 + wave;          // group within batch 0..127
    long g = (long)b * 128 + gwb;
    const float* sqb = sqv + ((long)b << 11);

    uint4 A[6];
    #pragma unroll
    for (int f = 0; f < 6; f++)
        A[f] = HsF[(g * 6 + f) * 64 + lane];

    float4 val[4]; int4 idx[4];
    #pragma unroll
    for (int r = 0; r < 4; r++) {
        val[r] = make_float4(3.4e38f, 3.4e38f, 3.4e38f, 3.4e38f);
        idx[r] = make_int4(0x7fffffff, 0x7fffffff, 0x7fffffff, 0x7fffffff);
    }

    int jg0 = js * 32;
    #pragma unroll
    for (int t = 0; t < 32; t++) {
        int G = jg0 + t;
        long fb = ((long)b * 128 + G) * 6;
        uint4 B[6];
        #pragma unroll
        for (int f = 0; f < 6; f++)
            B[f] = HsF[(fb + f) * 64 + lane];
        float sj = sqb[G * 16 + l15];

        // d = sj - 2*dot (row-constant +si shift dropped: ordering & ties unaffected)
        f32x4 acc = {0.f, 0.f, 0.f, 0.f};
        #pragma unroll
        for (int hf = 0; hf < 2; hf++) {
            acc = mfma16(A[hf],     B[hf],     acc);
            acc = mfma16(A[hf],     B[2 + hf], acc);
            acc = mfma16(A[2 + hf], B[hf],     acc);
            acc = mfma16(A[2 + hf], B[2 + hf], acc);
            acc = mfma16(A[hf],     B[4 + hf], acc);
            acc = mfma16(A[4 + hf], B[hf],     acc);
        }
        int j = G * 16 + l15;
        #pragma unroll
        for (int r = 0; r < 4; r++) {
            float d = fmaf(-2.f, acc[r], sj);
            INS4S(val[r], idx[r], d, j);
        }
    }

    // register butterfly merge over the 16 j-lanes (same quad => same rows)
    #pragma unroll
    for (int m = 1; m <= 8; m <<= 1) {
        #pragma unroll
        for (int r = 0; r < 4; r++) {
            float ov0 = __shfl_xor(val[r].x, m, 64), ov1 = __shfl_xor(val[r].y, m, 64);
            float ov2 = __shfl_xor(val[r].z, m, 64), ov3 = __shfl_xor(val[r].w, m, 64);
            int   oi0 = __shfl_xor(idx[r].x, m, 64), oi1 = __shfl_xor(idx[r].y, m, 64);
            int   oi2 = __shfl_xor(idx[r].z, m, 64), oi3 = __shfl_xor(idx[r].w, m, 64);
            INS4(val[r], idx[r], ov0, oi0); INS4(val[r], idx[r], ov1, oi1);
            INS4(val[r], idx[r], ov2, oi2); INS4(val[r], idx[r], ov3, oi3);
        }
    }
    if (l15 == 0) {
        #pragma unroll
        for (int r = 0; r < 4; r++) {
            long node = ((long)b << 11) + gwb * 16 + quad * 4 + r;
            u64* dst = pk + node * 16 + js * 4;
            reinterpret_cast<ulonglong2*>(dst)[0] =
                make_ulonglong2(packdj(val[r].x, idx[r].x), packdj(val[r].y, idx[r].y));
            reinterpret_cast<ulonglong2*>(dst)[1] =
                make_ulonglong2(packdj(val[r].z, idx[r].z), packdj(val[r].w, idx[r].w));
        }
    }
}

// ---------------- Kernel 3: fused split-merge + head (bf16 MFMA GEMMs) ----------------
// Block = 4 waves = 4 groups (64 nodes). Weight frags from global wfrag (pre-packed).
__global__ __launch_bounds__(256) void k_head(
    const uint4* __restrict__ HsF, const u64* __restrict__ pk, const uint4* __restrict__ wfrag,
    const float* __restrict__ bm, const float* __restrict__ bu1, const float* __restrict__ bu2,
    const float* __restrict__ Wmean, const float* __restrict__ bmean,
    const float* __restrict__ Wv, const float* __restrict__ bv,
    const float* __restrict__ log_std,
    float* __restrict__ out_mean, float* __restrict__ out_std, float* __restrict__ out_val)
{
    __shared__ __align__(16) unsigned short hcT[4][16 * 136]; // 17.4 KB

    int tid = threadIdx.x;
    int wave = tid >> 6, lane = tid & 63;
    int l15 = lane & 15, quad = lane >> 4;
    long g = blockIdx.x * 4 + wave;      // group 0..1023
    int b = (int)(g >> 7);

    // ---- fused 4-split merge for node = g*16 + l15 ----
    int nb[3];
    {
        const u64* src = pk + ((long)g * 16 + l15) * 16 + quad * 4;
        ulonglong2 a01 = reinterpret_cast<const ulonglong2*>(src)[0];
        ulonglong2 a23 = reinterpret_cast<const ulonglong2*>(src)[1];
        u64 m0 = a01.x, m1 = a01.y, m2 = a23.x, m3 = a23.y;  // sorted within split
        #pragma unroll
        for (int m = 16; m <= 32; m <<= 1) {
            u64 p0 = __shfl_xor(m0, m, 64), p1 = __shfl_xor(m1, m, 64);
            u64 p2 = __shfl_xor(m2, m, 64), p3 = __shfl_xor(m3, m, 64);
            INSQ(m0, m1, m2, m3, p0); INSQ(m0, m1, m2, m3, p1);
            INSQ(m0, m1, m2, m3, p2); INSQ(m0, m1, m2, m3, p3);
        }
        nb[0] = (int)(unsigned int)m1;   // drop rank 0 (self)
        nb[1] = (int)(unsigned int)m2;
        nb[2] = (int)(unsigned int)m3;
    }

    // ---- gather A-frags: own h + 3 neighbors, exact-reconstruct then RNE ----
    uint4 hA[2];
    #pragma unroll
    for (int hf = 0; hf < 2; hf++)
        hA[hf] = rne_merge(HsF[(g * 6 + hf) * 64 + lane],
                           HsF[(g * 6 + 2 + hf) * 64 + lane],
                           HsF[(g * 6 + 4 + hf) * 64 + lane]);
    uint4 nA[3][2];
    #pragma unroll
    for (int e = 0; e < 3; e++) {
        int jn = nb[e];
        long gj = (long)b * 128 + (jn >> 4);
        int ln2 = quad * 16 + (jn & 15);
        #pragma unroll
        for (int hf = 0; hf < 2; hf++)
            nA[e][hf] = rne_merge(HsF[(gj * 6 + hf) * 64 + ln2],
                                  HsF[(gj * 6 + 2 + hf) * 64 + ln2],
                                  HsF[(gj * 6 + 4 + hf) * 64 + ln2]);
    }
    // own h into hcT (row = l15, cols hf*32+quad*8..+7)
    #pragma unroll
    for (int hf = 0; hf < 2; hf++)
        *reinterpret_cast<uint4*>(&hcT[wave][l15 * 136 + hf * 32 + quad * 8]) = hA[hf];
    __syncthreads();

    // ---- msgs GEMM ----
    {
        uint4 wm_r[4][2];
        #pragma unroll
        for (int fg = 0; fg < 4; fg++)
            #pragma unroll
            for (int hf = 0; hf < 2; hf++)
                wm_r[fg][hf] = wfrag[(fg * 2 + hf) * 64 + lane];
        float bmv[4];
        #pragma unroll
        for (int fg = 0; fg < 4; fg++) bmv[fg] = bm[fg * 16 + l15];
        f32x4 msum[4];
        #pragma unroll
        for (int fg = 0; fg < 4; fg++) msum[fg] = (f32x4){0.f, 0.f, 0.f, 0.f};
        #pragma unroll
        for (int e = 0; e < 3; e++)
            #pragma unroll
            for (int fg = 0; fg < 4; fg++) {
                f32x4 c = {0.f, 0.f, 0.f, 0.f};
                c = mfma16(nA[e][0], wm_r[fg][0], c);
                c = mfma16(nA[e][1], wm_r[fg][1], c);
                #pragma unroll
                for (int r = 0; r < 4; r++) msum[fg][r] += fmaxf(c[r] + bmv[fg], 0.f);
            }
        #pragma unroll
        for (int fg = 0; fg < 4; fg++)
            #pragma unroll
            for (int r = 0; r < 4; r++)
                hcT[wave][(quad * 4 + r) * 136 + 64 + fg * 16 + l15] = f2bf_rne(msum[fg][r] * (1.f / 3.f));
    }
    __syncthreads();

    // ---- u1 GEMM ----
    {
        uint4 a1[4];
        #pragma unroll
        for (int kq = 0; kq < 4; kq++)
            a1[kq] = *reinterpret_cast<const uint4*>(&hcT[wave][l15 * 136 + kq * 32 + quad * 8]);
        unsigned short u1s[8][4];
        #pragma unroll
        for (int fg = 0; fg < 8; fg++) {
            float bv1 = bu1[fg * 16 + l15];
            f32x4 c = {0.f, 0.f, 0.f, 0.f};
            #pragma unroll
            for (int kq = 0; kq < 4; kq++)
                c = mfma16(a1[kq], wfrag[512 + (fg * 4 + kq) * 64 + lane], c);
            #pragma unroll
            for (int r = 0; r < 4; r++) u1s[fg][r] = f2bf_rne(fmaxf(c[r] + bv1, 0.f));
        }
        __syncthreads();
        #pragma unroll
        for (int fg = 0; fg < 8; fg++)
            #pragma unroll
            for (int r = 0; r < 4; r++)
                hcT[wave][(quad * 4 + r) * 136 + fg * 16 + l15] = u1s[fg][r];
    }
    __syncthreads();

    // ---- u2 GEMM ----
    float u2v[8][4];
    {
        uint4 a2[4];
        #pragma unroll
        for (int kq = 0; kq < 4; kq++)
            a2[kq] = *reinterpret_cast<const uint4*>(&hcT[wave][l15 * 136 + kq * 32 + quad * 8]);
        #pragma unroll
        for (int fg = 0; fg < 8; fg++) {
            float bv2 = bu2[fg * 16 + l15];
            f32x4 c = {0.f, 0.f, 0.f, 0.f};
            #pragma unroll
            for (int kq = 0; kq < 4; kq++)
                c = mfma16(a2[kq], wfrag[2560 + (fg * 4 + kq) * 64 + lane], c);
            #pragma unroll
            for (int r = 0; r < 4; r++) u2v[fg][r] = fmaxf(c[r] + bv2, 0.f);
        }
    }

    // ---- heads (fp32 VALU + 16-lane reduce) ----
    {
        float wm0[8], wm1[8], wvv[8];
        #pragma unroll
        for (int fg = 0; fg < 8; fg++) {
            int f = fg * 16 + l15;
            wm0[fg] = Wmean[f * 2 + 0];
            wm1[fg] = Wmean[f * 2 + 1];
            wvv[fg] = Wv[f];
        }
        float bm0 = bmean[0], bm1 = bmean[1], bv0 = bv[0];
        #pragma unroll
        for (int r = 0; r < 4; r++) {
            float p0 = 0.f, p1 = 0.f, p2 = 0.f;
            #pragma unroll
            for (int fg = 0; fg < 8; fg++) {
                p0 = fmaf(u2v[fg][r], wm0[fg], p0);
                p1 = fmaf(u2v[fg][r], wm1[fg], p1);
                p2 = fmaf(u2v[fg][r], wvv[fg], p2);
            }
            #pragma unroll
            for (int m = 1; m < 16; m <<= 1) {
                p0 += __shfl_xor(p0, m, 64);
                p1 += __shfl_xor(p1, m, 64);
                p2 += __shfl_xor(p2, m, 64);
            }
            if (l15 == 0) {
                int node = (int)g * 16 + quad * 4 + r;
                out_mean[node * 2 + 0] = p0 + bm0;
                out_mean[node * 2 + 1] = p1 + bm1;
                out_val[node] = p2 + bv0;
            }
        }
    }
    if (blockIdx.x == 0 && tid < 2) out_std[tid] = expf(log_std[tid]);
}

extern "C" void kernel_launch(void* const* d_in, const int* in_sizes, int n_in,
                              void* d_out, int out_size, void* d_ws, size_t ws_size,
                              hipStream_t stream) {
    const float* x     = (const float*)d_in[0];
    const float* W1    = (const float*)d_in[1];
    const float* b1    = (const float*)d_in[2];
    const float* W2    = (const float*)d_in[3];
    const float* b2    = (const float*)d_in[4];
    const float* Wm    = (const float*)d_in[5];
    const float* bm    = (const float*)d_in[6];
    const float* Wu1   = (const float*)d_in[7];
    const float* bu1   = (const float*)d_in[8];
    const float* Wu2   = (const float*)d_in[9];
    const float* bu2   = (const float*)d_in[10];
    const float* Wmean = (const float*)d_in[11];
    const float* bmean = (const float*)d_in[12];
    const float* Wv    = (const float*)d_in[13];
    const float* bv    = (const float*)d_in[14];
    const float* lstd  = (const float*)d_in[15];

    float* out = (float*)d_out;
    float* out_mean = out;                 // 8*2048*2
    float* out_std  = out + 32768;         // 2
    float* out_val  = out + 32770;         // 8*2048

    // workspace: 8,527,872 B total (< proven 8,650,752)
    uint4* HsF   = (uint4*)d_ws;                             // 6,291,456 B
    float* sqv   = (float*)(HsF + (long)1024 * 6 * 64);      // 65,536 B
    uint4* wfrag = (uint4*)(sqv + 16384);                    // 73,728 B
    u64*   pk    = (u64*)(wfrag + 4608);                     // 2,097,152 B

    k_wprep<<<18, 256, 0, stream>>>(Wm, Wu1, Wu2, wfrag);
    k_embed<<<1024, 256, 0, stream>>>(x, W1, b1, W2, b2, HsF, sqv);
    k_knn<<<1024, 256, 0, stream>>>(HsF, sqv, pk);
    k_head<<<256, 256, 0, stream>>>(HsF, pk, wfrag, bm, bu1, bu2,
                                    Wmean, bmean, Wv, bv, lstd,
                                    out_mean, out_std, out_val);
}

// Round 12
// 196.688 us; speedup vs baseline: 3.3850x; 3.3850x over previous
//
#include <hip/hip_runtime.h>
#include <math.h>

#define NB 8
#define NN 2048

typedef short bf16x8 __attribute__((ext_vector_type(8)));
typedef float f32x4  __attribute__((ext_vector_type(4)));
typedef unsigned long long u64;

__device__ __forceinline__ f32x4 mfma16(uint4 a, uint4 b, f32x4 c) {
    return __builtin_amdgcn_mfma_f32_16x16x32_bf16(
        __builtin_bit_cast(bf16x8, a), __builtin_bit_cast(bf16x8, b), c, 0, 0, 0);
}

__device__ __forceinline__ float bf2f(unsigned short u) {
    unsigned int t = ((unsigned int)u) << 16;
    return __builtin_bit_cast(float, t);
}

__device__ __forceinline__ unsigned short f2bf_rne(float f) {
    unsigned int u = __builtin_bit_cast(unsigned int, f);
    return (unsigned short)((u + 0x7FFFu + ((u >> 16) & 1u)) >> 16);
}

__device__ __forceinline__ unsigned int rne_pair(unsigned int a, unsigned int b, unsigned int c) {
    float lo = bf2f((unsigned short)(a & 0xFFFF)) + bf2f((unsigned short)(b & 0xFFFF)) + bf2f((unsigned short)(c & 0xFFFF));
    float hi = bf2f((unsigned short)(a >> 16)) + bf2f((unsigned short)(b >> 16)) + bf2f((unsigned short)(c >> 16));
    return (unsigned int)f2bf_rne(lo) | ((unsigned int)f2bf_rne(hi) << 16);
}
__device__ __forceinline__ uint4 rne_merge(uint4 a, uint4 b, uint4 c) {
    return make_uint4(rne_pair(a.x, b.x, c.x), rne_pair(a.y, b.y, c.y),
                      rne_pair(a.z, b.z, c.z), rne_pair(a.w, b.w, c.w));
}

// monotone float->u32 key (ascending), then <<32 | j: u64 compare == (d, j) lexicographic
__device__ __forceinline__ u64 packdj(float d, int j) {
    unsigned int u = __builtin_bit_cast(unsigned int, d);
    unsigned int key = u ^ ((unsigned int)(((int)u) >> 31) | 0x80000000u);
    return ((u64)key << 32) | (unsigned int)j;
}

// Full sorted insert with jax tie-break (equal d -> smaller j) — for merges.
#define INS4(vv, ii, d, j) {                                      \
    bool c0 = (d < vv.x) || (d == vv.x && j < ii.x);              \
    bool c1 = (d < vv.y) || (d == vv.y && j < ii.y);              \
    bool c2 = (d < vv.z) || (d == vv.z && j < ii.z);              \
    bool c3 = (d < vv.w) || (d == vv.w && j < ii.w);              \
    vv.w = c3 ? (c2 ? vv.z : d) : vv.w; ii.w = c3 ? (c2 ? ii.z : j) : ii.w; \
    vv.z = c2 ? (c1 ? vv.y : d) : vv.z; ii.z = c2 ? (c1 ? ii.y : j) : ii.z; \
    vv.y = c1 ? (c0 ? vv.x : d) : vv.y; ii.y = c1 ? (c0 ? ii.x : j) : ii.y; \
    vv.x = c0 ? d : vv.x;               ii.x = c0 ? j : ii.x; }

// Strict-< insert: valid when candidates arrive in ascending j within a lane.
#define INS4S(vv, ii, d, j) {                                     \
    bool c0 = (d < vv.x); bool c1 = (d < vv.y);                   \
    bool c2 = (d < vv.z); bool c3 = (d < vv.w);                   \
    vv.w = c3 ? (c2 ? vv.z : d) : vv.w; ii.w = c3 ? (c2 ? ii.z : j) : ii.w; \
    vv.z = c2 ? (c1 ? vv.y : d) : vv.z; ii.z = c2 ? (c1 ? ii.y : j) : ii.z; \
    vv.y = c1 ? (c0 ? vv.x : d) : vv.y; ii.y = c1 ? (c0 ? ii.x : j) : ii.y; \
    vv.x = c0 ? d : vv.x;               ii.x = c0 ? j : ii.x; }

// sorted-4 u64 insert (strict <; entries are unique)
#define INSQ(a0, a1, a2, a3, p) {                                 \
    bool c0 = (p) < a0; bool c1 = (p) < a1;                       \
    bool c2 = (p) < a2; bool c3 = (p) < a3;                       \
    a3 = c3 ? (c2 ? a2 : (p)) : a3;                               \
    a2 = c2 ? (c1 ? a1 : (p)) : a2;                               \
    a1 = c1 ? (c0 ? a0 : (p)) : a1;                               \
    a0 = c0 ? (p) : a0; }

// ---------------- Kernel 0: weights -> bf16 MFMA B-frag images in workspace ----------------
// wfrag: [0,512) Wm frags; [512,2560) Wu1; [2560,4608) Wu2.
__global__ __launch_bounds__(256) void k_wprep(
    const float* __restrict__ Wm, const float* __restrict__ Wu1, const float* __restrict__ Wu2,
    uint4* __restrict__ wfrag)
{
    int q = blockIdx.x * 256 + threadIdx.x;   // 0..4607
    int ln = q & 63;
    int fr = ln & 15, qd = ln >> 4;
    unsigned int p[4];
    if (q < 512) {
        int fi2 = q >> 6;
        int fg = fi2 >> 1, hf = fi2 & 1;
        #pragma unroll
        for (int e2 = 0; e2 < 4; e2++) {
            unsigned int lo = f2bf_rne(Wm[(hf * 32 + qd * 8 + e2 * 2 + 0) * 64 + fg * 16 + fr]);
            unsigned int hi = f2bf_rne(Wm[(hf * 32 + qd * 8 + e2 * 2 + 1) * 64 + fg * 16 + fr]);
            p[e2] = lo | (hi << 16);
        }
    } else {
        int qq = q - 512;
        const float* W = (qq < 2048) ? Wu1 : Wu2;
        int q2 = qq & 2047;
        int fi2 = q2 >> 6;
        int fg = fi2 >> 2, kq = fi2 & 3;
        #pragma unroll
        for (int e2 = 0; e2 < 4; e2++) {
            unsigned int lo = f2bf_rne(W[(kq * 32 + qd * 8 + e2 * 2 + 0) * 128 + fg * 16 + fr]);
            unsigned int hi = f2bf_rne(W[(kq * 32 + qd * 8 + e2 * 2 + 1) * 128 + fg * 16 + fr]);
            p[e2] = lo | (hi << 16);
        }
    }
    wfrag[q] = make_uint4(p[0], p[1], p[2], p[3]);
}

// ---------------- Kernel 1: embed MLP; emit frag-major 3-split HsF + sq ----------------
__global__ __launch_bounds__(256) void k_embed(
    const float* __restrict__ x, const float* __restrict__ W1, const float* __restrict__ b1,
    const float* __restrict__ W2, const float* __restrict__ b2,
    uint4* __restrict__ HsF, float* __restrict__ sqv)
{
    __shared__ float w2s[4096];
    __shared__ float h1s[4][4][64];
    __shared__ unsigned short sh[3 * 16 * 72];
    int tid = threadIdx.x;
    for (int q = tid; q < 4096; q += 256) w2s[q] = W2[q];
    int wave = tid >> 6, lane = tid & 63;
    int nbase = blockIdx.x * 16 + wave * 4;
    float w10 = W1[lane], w11 = W1[64 + lane], w12 = W1[128 + lane], w13 = W1[192 + lane];
    float b1l = b1[lane];
    #pragma unroll
    for (int v = 0; v < 4; v++) {
        float4 xv = reinterpret_cast<const float4*>(x)[nbase + v];
        h1s[wave][v][lane] = fmaxf(b1l + xv.x * w10 + xv.y * w11 + xv.z * w12 + xv.w * w13, 0.f);
    }
    __syncthreads();
    float b2l = b2[lane];
    float a0 = b2l, a1 = b2l, a2 = b2l, a3 = b2l;
    for (int k = 0; k < 64; k++) {
        float w = w2s[k * 64 + lane];
        a0 += h1s[wave][0][k] * w; a1 += h1s[wave][1][k] * w;
        a2 += h1s[wave][2][k] * w; a3 += h1s[wave][3][k] * w;
    }
    float hvs[4] = {fmaxf(a0, 0.f), fmaxf(a1, 0.f), fmaxf(a2, 0.f), fmaxf(a3, 0.f)};
    #pragma unroll
    for (int v = 0; v < 4; v++) {
        float hval = hvs[v];
        long node = nbase + v;
        int row = wave * 4 + v;
        unsigned int u0 = __builtin_bit_cast(unsigned int, hval);
        unsigned short s0 = (unsigned short)(u0 >> 16);
        float f0 = __builtin_bit_cast(float, u0 & 0xFFFF0000u);
        float r1 = hval - f0;
        unsigned int u1 = __builtin_bit_cast(unsigned int, r1);
        unsigned short s1 = (unsigned short)(u1 >> 16);
        float f1 = __builtin_bit_cast(float, u1 & 0xFFFF0000u);
        float r2 = r1 - f1;
        unsigned short s2 = (unsigned short)(__builtin_bit_cast(unsigned int, r2) >> 16);
        sh[(0 * 16 + row) * 72 + lane] = s0;
        sh[(1 * 16 + row) * 72 + lane] = s1;
        sh[(2 * 16 + row) * 72 + lane] = s2;
        float s = hval * hval;
        #pragma unroll
        for (int m = 1; m < 64; m <<= 1) s += __shfl_xor(s, m, 64);
        if (lane == 0) sqv[node] = s;
    }
    __syncthreads();
    for (int q = tid; q < 384; q += 256) {
        int f = q >> 6, ln = q & 63;
        int s = f >> 1, hf = f & 1;
        int row = ln & 15, eb = hf * 32 + (ln >> 4) * 8;
        const unsigned short* sp = &sh[(s * 16 + row) * 72 + eb];
        unsigned int p0 = (unsigned int)sp[0] | ((unsigned int)sp[1] << 16);
        unsigned int p1 = (unsigned int)sp[2] | ((unsigned int)sp[3] << 16);
        unsigned int p2 = (unsigned int)sp[4] | ((unsigned int)sp[5] << 16);
        unsigned int p3 = (unsigned int)sp[6] | ((unsigned int)sp[7] << 16);
        HsF[((long)blockIdx.x * 6 + f) * 64 + ln] = make_uint4(p0, p1, p2, p3);
    }
}

// ---------------- Kernel 2: 3-NN partials via MFMA (round-10 proven structure) ----------------
// Block: 4 waves = 4 consecutive i-groups sweeping the SAME j-split (B frags L1-shared).
// Rolled 16-iter loop (#pragma unroll 1) — full unroll spills (round-11 lesson).
__global__ __launch_bounds__(256, 3) void k_knn(
    const uint4* __restrict__ HsF, const float* __restrict__ sqv,
    u64* __restrict__ pk)
{
    __shared__ float smv[4][1056];
    __shared__ int   smi[4][1056];

    int tid = threadIdx.x;
    int wave = tid >> 6, lane = tid & 63;
    int l15 = lane & 15, quad = lane >> 4;

    int bx = blockIdx.x;                 // 0..1023
    int js = bx & 3;
    int gquad = (bx >> 2) & 31;
    int b = bx >> 7;
    int gwb = gquad * 4 + wave;          // group within batch 0..127
    long g = (long)b * 128 + gwb;
    const float* sqb = sqv + ((long)b << 11);

    uint4 A[6];
    #pragma unroll
    for (int f = 0; f < 6; f++)
        A[f] = HsF[(g * 6 + f) * 64 + lane];

    float4 val[4]; int4 idx[4];
    #pragma unroll
    for (int r = 0; r < 4; r++) {
        val[r] = make_float4(3.4e38f, 3.4e38f, 3.4e38f, 3.4e38f);
        idx[r] = make_int4(0x7fffffff, 0x7fffffff, 0x7fffffff, 0x7fffffff);
    }

#define LOADB(B, SJ, G) {                                                     \
    long fb = ((long)b * 128 + (G)) * 6;                                      \
    _Pragma("unroll")                                                         \
    for (int f = 0; f < 6; f++)                                               \
        B[f] = HsF[(fb + f) * 64 + lane];                                     \
    SJ = sqb[(G) * 16 + l15]; }

// d = sj - 2*dot (the +si shift is row-constant: ordering & ties unaffected)
#define COMPUTE(B, SJ, G) {                                                   \
    int j = (G) * 16 + l15;                                                   \
    f32x4 acc = {0.f, 0.f, 0.f, 0.f};                                         \
    _Pragma("unroll")                                                         \
    for (int hf = 0; hf < 2; hf++) {                                          \
        acc = mfma16(A[hf],     B[hf],     acc);                              \
        acc = mfma16(A[hf],     B[2 + hf], acc);                              \
        acc = mfma16(A[2 + hf], B[hf],     acc);                              \
        acc = mfma16(A[2 + hf], B[2 + hf], acc);                              \
        acc = mfma16(A[hf],     B[4 + hf], acc);                              \
        acc = mfma16(A[4 + hf], B[hf],     acc);                              \
    }                                                                         \
    _Pragma("unroll")                                                         \
    for (int r = 0; r < 4; r++) {                                             \
        float d = fmaf(-2.f, acc[r], SJ);                                     \
        INS4S(val[r], idx[r], d, j);                                          \
    } }

    int jg0 = js * 32;
    uint4 B0[6], B1[6];
    float sj0, sj1;
    LOADB(B0, sj0, jg0);
    #pragma unroll 1
    for (int t = 0; t < 16; t++) {
        int ga = jg0 + t * 2;
        int gbn = ga + 1;
        int gc = jg0 + ((t * 2 + 2) & 31);   // wraps on last iter (dummy prefetch)
        LOADB(B1, sj1, gbn);
        COMPUTE(B0, sj0, ga);
        LOADB(B0, sj0, gc);
        COMPUTE(B1, sj1, gbn);
    }

    // single-phase merge (round-4 proven): stash 16 rows x 16 lists x 4
    float* mv = smv[wave]; int* mi = smi[wave];
    #pragma unroll
    for (int r = 0; r < 4; r++) {
        int base = (quad * 4 + r) * 65 + l15 * 4;
        mv[base + 0] = val[r].x; mv[base + 1] = val[r].y;
        mv[base + 2] = val[r].z; mv[base + 3] = val[r].w;
        mi[base + 0] = idx[r].x; mi[base + 1] = idx[r].y;
        mi[base + 2] = idx[r].z; mi[base + 3] = idx[r].w;
    }
    __syncthreads();
    float4 fv = make_float4(3.4e38f, 3.4e38f, 3.4e38f, 3.4e38f);
    int4   fi = make_int4(0x7fffffff, 0x7fffffff, 0x7fffffff, 0x7fffffff);
    #pragma unroll
    for (int tt = 0; tt < 4; tt++) {
        int base = l15 * 65 + (quad * 4 + tt) * 4;
        #pragma unroll
        for (int k = 0; k < 4; k++) {
            float d = mv[base + k];
            int j = mi[base + k];
            INS4(fv, fi, d, j);
        }
    }
    #pragma unroll
    for (int m = 16; m <= 32; m <<= 1) {
        float ov0 = __shfl_xor(fv.x, m, 64), ov1 = __shfl_xor(fv.y, m, 64);
        float ov2 = __shfl_xor(fv.z, m, 64), ov3 = __shfl_xor(fv.w, m, 64);
        int   oi0 = __shfl_xor(fi.x, m, 64), oi1 = __shfl_xor(fi.y, m, 64);
        int   oi2 = __shfl_xor(fi.z, m, 64), oi3 = __shfl_xor(fi.w, m, 64);
        INS4(fv, fi, ov0, oi0); INS4(fv, fi, ov1, oi1);
        INS4(fv, fi, ov2, oi2); INS4(fv, fi, ov3, oi3);
    }
    if (quad == 0) {
        long node = ((long)b << 11) + gwb * 16 + l15;
        u64* dst = pk + node * 16 + js * 4;
        reinterpret_cast<ulonglong2*>(dst)[0] =
            make_ulonglong2(packdj(fv.x, fi.x), packdj(fv.y, fi.y));
        reinterpret_cast<ulonglong2*>(dst)[1] =
            make_ulonglong2(packdj(fv.z, fi.z), packdj(fv.w, fi.w));
    }
}

// ---------------- Kernel 3: fused split-merge + head (bf16 MFMA GEMMs) ----------------
// Block = 4 waves = 4 groups (64 nodes). Weight frags from global wfrag (pre-packed).
__global__ __launch_bounds__(256) void k_head(
    const uint4* __restrict__ HsF, const u64* __restrict__ pk, const uint4* __restrict__ wfrag,
    const float* __restrict__ bm, const float* __restrict__ bu1, const float* __restrict__ bu2,
    const float* __restrict__ Wmean, const float* __restrict__ bmean,
    const float* __restrict__ Wv, const float* __restrict__ bv,
    const float* __restrict__ log_std,
    float* __restrict__ out_mean, float* __restrict__ out_std, float* __restrict__ out_val)
{
    __shared__ __align__(16) unsigned short hcT[4][16 * 136]; // 17.4 KB

    int tid = threadIdx.x;
    int wave = tid >> 6, lane = tid & 63;
    int l15 = lane & 15, quad = lane >> 4;
    long g = blockIdx.x * 4 + wave;      // group 0..1023
    int b = (int)(g >> 7);

    // ---- fused 4-split merge for node = g*16 + l15 ----
    int nb[3];
    {
        const u64* src = pk + ((long)g * 16 + l15) * 16 + quad * 4;
        ulonglong2 a01 = reinterpret_cast<const ulonglong2*>(src)[0];
        ulonglong2 a23 = reinterpret_cast<const ulonglong2*>(src)[1];
        u64 m0 = a01.x, m1 = a01.y, m2 = a23.x, m3 = a23.y;  // sorted within split
        #pragma unroll
        for (int m = 16; m <= 32; m <<= 1) {
            u64 p0 = __shfl_xor(m0, m, 64), p1 = __shfl_xor(m1, m, 64);
            u64 p2 = __shfl_xor(m2, m, 64), p3 = __shfl_xor(m3, m, 64);
            INSQ(m0, m1, m2, m3, p0); INSQ(m0, m1, m2, m3, p1);
            INSQ(m0, m1, m2, m3, p2); INSQ(m0, m1, m2, m3, p3);
        }
        nb[0] = (int)(unsigned int)m1;   // drop rank 0 (self)
        nb[1] = (int)(unsigned int)m2;
        nb[2] = (int)(unsigned int)m3;
    }

    // ---- gather A-frags: own h + 3 neighbors, exact-reconstruct then RNE ----
    uint4 hA[2];
    #pragma unroll
    for (int hf = 0; hf < 2; hf++)
        hA[hf] = rne_merge(HsF[(g * 6 + hf) * 64 + lane],
                           HsF[(g * 6 + 2 + hf) * 64 + lane],
                           HsF[(g * 6 + 4 + hf) * 64 + lane]);
    uint4 nA[3][2];
    #pragma unroll
    for (int e = 0; e < 3; e++) {
        int jn = nb[e];
        long gj = (long)b * 128 + (jn >> 4);
        int ln2 = quad * 16 + (jn & 15);
        #pragma unroll
        for (int hf = 0; hf < 2; hf++)
            nA[e][hf] = rne_merge(HsF[(gj * 6 + hf) * 64 + ln2],
                                  HsF[(gj * 6 + 2 + hf) * 64 + ln2],
                                  HsF[(gj * 6 + 4 + hf) * 64 + ln2]);
    }
    // own h into hcT (row = l15, cols hf*32+quad*8..+7)
    #pragma unroll
    for (int hf = 0; hf < 2; hf++)
        *reinterpret_cast<uint4*>(&hcT[wave][l15 * 136 + hf * 32 + quad * 8]) = hA[hf];
    __syncthreads();

    // ---- msgs GEMM ----
    {
        uint4 wm_r[4][2];
        #pragma unroll
        for (int fg = 0; fg < 4; fg++)
            #pragma unroll
            for (int hf = 0; hf < 2; hf++)
                wm_r[fg][hf] = wfrag[(fg * 2 + hf) * 64 + lane];
        float bmv[4];
        #pragma unroll
        for (int fg = 0; fg < 4; fg++) bmv[fg] = bm[fg * 16 + l15];
        f32x4 msum[4];
        #pragma unroll
        for (int fg = 0; fg < 4; fg++) msum[fg] = (f32x4){0.f, 0.f, 0.f, 0.f};
        #pragma unroll
        for (int e = 0; e < 3; e++)
            #pragma unroll
            for (int fg = 0; fg < 4; fg++) {
                f32x4 c = {0.f, 0.f, 0.f, 0.f};
                c = mfma16(nA[e][0], wm_r[fg][0], c);
                c = mfma16(nA[e][1], wm_r[fg][1], c);
                #pragma unroll
                for (int r = 0; r < 4; r++) msum[fg][r] += fmaxf(c[r] + bmv[fg], 0.f);
            }
        #pragma unroll
        for (int fg = 0; fg < 4; fg++)
            #pragma unroll
            for (int r = 0; r < 4; r++)
                hcT[wave][(quad * 4 + r) * 136 + 64 + fg * 16 + l15] = f2bf_rne(msum[fg][r] * (1.f / 3.f));
    }
    __syncthreads();

    // ---- u1 GEMM ----
    {
        uint4 a1[4];
        #pragma unroll
        for (int kq = 0; kq < 4; kq++)
            a1[kq] = *reinterpret_cast<const uint4*>(&hcT[wave][l15 * 136 + kq * 32 + quad * 8]);
        unsigned short u1s[8][4];
        #pragma unroll
        for (int fg = 0; fg < 8; fg++) {
            float bv1 = bu1[fg * 16 + l15];
            f32x4 c = {0.f, 0.f, 0.f, 0.f};
            #pragma unroll
            for (int kq = 0; kq < 4; kq++)
                c = mfma16(a1[kq], wfrag[512 + (fg * 4 + kq) * 64 + lane], c);
            #pragma unroll
            for (int r = 0; r < 4; r++) u1s[fg][r] = f2bf_rne(fmaxf(c[r] + bv1, 0.f));
        }
        __syncthreads();
        #pragma unroll
        for (int fg = 0; fg < 8; fg++)
            #pragma unroll
            for (int r = 0; r < 4; r++)
                hcT[wave][(quad * 4 + r) * 136 + fg * 16 + l15] = u1s[fg][r];
    }
    __syncthreads();

    // ---- u2 GEMM ----
    float u2v[8][4];
    {
        uint4 a2[4];
        #pragma unroll
        for (int kq = 0; kq < 4; kq++)
            a2[kq] = *reinterpret_cast<const uint4*>(&hcT[wave][l15 * 136 + kq * 32 + quad * 8]);
        #pragma unroll
        for (int fg = 0; fg < 8; fg++) {
            float bv2 = bu2[fg * 16 + l15];
            f32x4 c = {0.f, 0.f, 0.f, 0.f};
            #pragma unroll
            for (int kq = 0; kq < 4; kq++)
                c = mfma16(a2[kq], wfrag[2560 + (fg * 4 + kq) * 64 + lane], c);
            #pragma unroll
            for (int r = 0; r < 4; r++) u2v[fg][r] = fmaxf(c[r] + bv2, 0.f);
        }
    }

    // ---- heads (fp32 VALU + 16-lane reduce) ----
    {
        float wm0[8], wm1[8], wvv[8];
        #pragma unroll
        for (int fg = 0; fg < 8; fg++) {
            int f = fg * 16 + l15;
            wm0[fg] = Wmean[f * 2 + 0];
            wm1[fg] = Wmean[f * 2 + 1];
            wvv[fg] = Wv[f];
        }
        float bm0 = bmean[0], bm1 = bmean[1], bv0 = bv[0];
        #pragma unroll
        for (int r = 0; r < 4; r++) {
            float p0 = 0.f, p1 = 0.f, p2 = 0.f;
            #pragma unroll
            for (int fg = 0; fg < 8; fg++) {
                p0 = fmaf(u2v[fg][r], wm0[fg], p0);
                p1 = fmaf(u2v[fg][r], wm1[fg], p1);
                p2 = fmaf(u2v[fg][r], wvv[fg], p2);
            }
            #pragma unroll
            for (int m = 1; m < 16; m <<= 1) {
                p0 += __shfl_xor(p0, m, 64);
                p1 += __shfl_xor(p1, m, 64);
                p2 += __shfl_xor(p2, m, 64);
            }
            if (l15 == 0) {
                int node = (int)g * 16 + quad * 4 + r;
                out_mean[node * 2 + 0] = p0 + bm0;
                out_mean[node * 2 + 1] = p1 + bm1;
                out_val[node] = p2 + bv0;
            }
        }
    }
    if (blockIdx.x == 0 && tid < 2) out_std[tid] = expf(log_std[tid]);
}

extern "C" void kernel_launch(void* const* d_in, const int* in_sizes, int n_in,
                              void* d_out, int out_size, void* d_ws, size_t ws_size,
                              hipStream_t stream) {
    const float* x     = (const float*)d_in[0];
    const float* W1    = (const float*)d_in[1];
    const float* b1    = (const float*)d_in[2];
    const float* W2    = (const float*)d_in[3];
    const float* b2    = (const float*)d_in[4];
    const float* Wm    = (const float*)d_in[5];
    const float* bm    = (const float*)d_in[6];
    const float* Wu1   = (const float*)d_in[7];
    const float* bu1   = (const float*)d_in[8];
    const float* Wu2   = (const float*)d_in[9];
    const float* bu2   = (const float*)d_in[10];
    const float* Wmean = (const float*)d_in[11];
    const float* bmean = (const float*)d_in[12];
    const float* Wv    = (const float*)d_in[13];
    const float* bv    = (const float*)d_in[14];
    const float* lstd  = (const float*)d_in[15];

    float* out = (float*)d_out;
    float* out_mean = out;                 // 8*2048*2
    float* out_std  = out + 32768;         // 2
    float* out_val  = out + 32770;         // 8*2048

    // workspace: 8,527,872 B total (< proven 8,650,752)
    uint4* HsF   = (uint4*)d_ws;                             // 6,291,456 B
    float* sqv   = (float*)(HsF + (long)1024 * 6 * 64);      // 65,536 B
    uint4* wfrag = (uint4*)(sqv + 16384);                    // 73,728 B
    u64*   pk    = (u64*)(wfrag + 4608);                     // 2,097,152 B

    k_wprep<<<18, 256, 0, stream>>>(Wm, Wu1, Wu2, wfrag);
    k_embed<<<1024, 256, 0, stream>>>(x, W1, b1, W2, b2, HsF, sqv);
    k_knn<<<1024, 256, 0, stream>>>(HsF, sqv, pk);
    k_head<<<256, 256, 0, stream>>>(HsF, pk, wfrag, bm, bu1, bu2,
                                    Wmean, bmean, Wv, bv, lstd,
                                    out_mean, out_std, out_val);
}